// Round 3
// baseline (523.859 us; speedup 1.0000x reference)
//
#include <hip/hip_runtime.h>
#include <cstdint>
#include <cstddef>

// ---------------------------------------------------------------------------
// feature_matching: corr(P=20, C=64) -> 4x (depthwise 3^3 + pointwise) blocks
//
// R3: fused_block v3 — DT=2 d-plane tiling with merged plane loop (input
// planes loaded once feed all overlapping kd taps), scalar halo loads,
// bf16 LDS for dw intermediates, full-256-thread pointwise phase.
// corr path (transpose + MFMA band) unchanged from R2.
//
// ws layout (peak 157,286,400 B):
//   [0,        78.6MB): corrO (bf16)        -> later b2o (fp32, 39.3MB)
//   [78.6MB,  157.3MB): rgbT+depT (bf16)    -> later b1o (bf16, 78.6MB)
//                                           -> later b3o (fp32, 39.3MB)
// ---------------------------------------------------------------------------

typedef unsigned short bf16_t;
typedef __attribute__((ext_vector_type(8))) short short8;
typedef __attribute__((ext_vector_type(4))) float f32x4;

static __device__ inline float b2f(bf16_t u) {
    union { float f; uint32_t i; } v; v.i = ((uint32_t)u) << 16; return v.f;
}
static __device__ inline bf16_t f2b(float f) {
    union { float f; uint32_t i; } v; v.f = f;
    uint32_t r = v.i + 0x7fffu + ((v.i >> 16) & 1u);  // round-nearest-even
    return (bf16_t)(r >> 16);
}

static __device__ inline float4 ld4(const float* p) { return *(const float4*)p; }
static __device__ inline float4 ld4(const bf16_t* p) {
    ushort4 u = *(const ushort4*)p;
    return make_float4(b2f(u.x), b2f(u.y), b2f(u.z), b2f(u.w));
}
static __device__ inline float ld1(const float* p) { return *p; }
static __device__ inline float ld1(const bf16_t* p) { return b2f(*p); }
static __device__ inline void st1(float* p, float v) { *p = v; }
static __device__ inline void st1(bf16_t* p, float v) { *p = f2b(v); }

// ---------------------------------------------------------------------------
// Prepass: (b,c,h,w) fp32 -> (b,h,w,c) bf16, LDS tile transpose per (b,h).
// ---------------------------------------------------------------------------
__global__ __launch_bounds__(256) void transpose_bf16(
        const float* __restrict__ rgb, const float* __restrict__ dep,
        bf16_t* __restrict__ rgbT, bf16_t* __restrict__ depT) {
    const int bh = blockIdx.x;
    const float* src = blockIdx.y ? dep : rgb;
    bf16_t* dst = blockIdx.y ? depT : rgbT;
    const int tid = threadIdx.x;
    const int b = bh >> 6, h = bh & 63;

    __shared__ bf16_t S[64 * 194];

    const float* srcb = src + (size_t)b * 786432 + (size_t)h * 192;
#pragma unroll
    for (int it = 0; it < 12; ++it) {
        const int idx = it * 256 + tid;      // 3072 = 64c x 48 float4
        const int c = idx / 48, w4 = idx - c * 48;
        const float4 v = *(const float4*)(srcb + (size_t)c * 12288 + 4 * w4);
        bf16_t* sp = &S[c * 194 + 4 * w4];
        sp[0] = f2b(v.x); sp[1] = f2b(v.y); sp[2] = f2b(v.z); sp[3] = f2b(v.w);
    }
    __syncthreads();
    bf16_t* dstb = dst + (size_t)bh * 192 * 64;
#pragma unroll
    for (int it = 0; it < 12; ++it) {
        const int idx = it * 256 + tid;      // 3072 = 192w x 16 c4
        const int w = idx >> 4, c4 = idx & 15;
        ushort4 o;
        o.x = S[(4 * c4 + 0) * 194 + w];
        o.y = S[(4 * c4 + 1) * 194 + w];
        o.z = S[(4 * c4 + 2) * 194 + w];
        o.w = S[(4 * c4 + 3) * 194 + w];
        *(ushort4*)(dstb + (size_t)w * 64 + 4 * c4) = o;
    }
}

// ---------------------------------------------------------------------------
// MFMA correlation (unchanged from R2).
// ---------------------------------------------------------------------------
__global__ __launch_bounds__(256) void corr_mfma(
        const bf16_t* __restrict__ rgbT, const bf16_t* __restrict__ depT,
        bf16_t* __restrict__ out) {
    const int di = blockIdx.x, h = blockIdx.y, b = blockIdx.z;
    const int tid = threadIdx.x;
    const int hd = h + di - 10;
    bf16_t* outb = out + ((size_t)((b * 20 + di) * 20) * 64 + h) * 192;

    if (hd < 0 || hd >= 64) {            // depth row fully in zero-pad
#pragma unroll
        for (int it = 0; it < 4; ++it) {
            const int idx = it * 256 + tid;
            if (idx < 960) {
                const int dj = idx / 48, w4 = idx - dj * 48;
                *(ushort4*)(outb + (size_t)dj * 12288 + 4 * w4) =
                    make_ushort4(0, 0, 0, 0);
            }
        }
        return;
    }

    __shared__ float Dall[4080];         // addr = w*21 + (w>>2) + dj
    const int lane = tid & 63, wave = tid >> 6;
    const int n = lane & 15, q = lane >> 4;

    const bf16_t* Abase = rgbT + (size_t)(b * 64 + h) * 192 * 64;
    const bf16_t* Bbase = depT + (size_t)(b * 64 + hd) * 192 * 64;

#pragma unroll
    for (int t = 0; t < 3; ++t) {
        const int w0 = wave * 48 + t * 16;
        const short8* Ap = (const short8*)(Abase + (size_t)(w0 + n) * 64 + q * 8);
        const short8 a0 = Ap[0];         // c = q*8 .. q*8+7
        const short8 a1 = Ap[4];         // c += 32
        f32x4 acc[3];
#pragma unroll
        for (int ut = 0; ut < 3; ++ut) {
            acc[ut].x = 0.f; acc[ut].y = 0.f; acc[ut].z = 0.f; acc[ut].w = 0.f;
        }
#pragma unroll
        for (int ut = 0; ut < 3; ++ut) {
            const int u0 = w0 + (ut - 1) * 16;
            if (u0 >= 0 && u0 <= 176) {  // wave-uniform; OOB tile stays 0
                const short8* Bp = (const short8*)(Bbase + (size_t)(u0 + n) * 64 + q * 8);
                acc[ut] = __builtin_amdgcn_mfma_f32_16x16x32_bf16(a0, Bp[0], acc[ut], 0, 0, 0);
                acc[ut] = __builtin_amdgcn_mfma_f32_16x16x32_bf16(a1, Bp[4], acc[ut], 0, 0, 0);
            }
        }
#pragma unroll
        for (int ut = 0; ut < 3; ++ut) {
#pragma unroll
            for (int r = 0; r < 4; ++r) {
                const int dj = 16 * ut + n - 4 * q - r - 6;
                const int w = w0 + 4 * q + r;
                if (dj >= 0 && dj < 20)
                    Dall[w * 21 + (w >> 2) + dj] = acc[ut][r];
            }
        }
    }
    __syncthreads();
#pragma unroll
    for (int it = 0; it < 4; ++it) {
        const int idx = it * 256 + tid;
        if (idx < 960) {
            const int dj = idx / 48, w4 = idx - dj * 48;
            const int base = 85 * w4 + dj;   // (4*w4+j)*21 + w4 + dj
            ushort4 o;
            o.x = f2b(Dall[base]);
            o.y = f2b(Dall[base + 21]);
            o.z = f2b(Dall[base + 42]);
            o.w = f2b(Dall[base + 63]);
            *(ushort4*)(outb + (size_t)dj * 12288 + 4 * w4) = o;
        }
    }
}

// ---------------------------------------------------------------------------
// Fused block v3: DT output d-planes per block, merged plane loop.
// Phase 1: task = (ci, w-quad); for each input plane p (NP = S*(DT-1)+3),
//   each row loaded ONCE feeds every (dl, kd = p - S*dl) tap combination.
//   acc[DT][4][4] fp32; bias+leaky; bf16 -> LDS sT[CIN][DT][4][48].
// Phase 2: DT*192 positions over 256 threads; pw weights wave-uniform
//   (s_load); fp32 accumulate; leaky; store.
// ---------------------------------------------------------------------------
template<int CIN, int COUT, int S, int DT, int DIN, int HIN, int WIN,
         int DO, int HO, int WO, typename TIN, typename TOUT>
__global__ __launch_bounds__(256) void fused_block(
        const TIN* __restrict__ x,
        const float* __restrict__ dw_w, const float* __restrict__ dw_b,
        const float* __restrict__ pw_w, const float* __restrict__ pw_b,
        TOUT* __restrict__ y) {
    static_assert(WO % 48 == 0 && HO % 4 == 0, "tile divisibility");
    constexpr int WT = WO / 48;
    const int wt = blockIdx.x % WT;
    const int ht = blockIdx.x / WT;
    const int d0 = blockIdx.y * DT;
    const int b  = blockIdx.z;
    const int tid = threadIdx.x;
    const int h0 = ht * 4;
    const int wbase = wt * 48;

    __shared__ float  sDW[CIN * 27];
    __shared__ float  sDB[CIN];
    __shared__ bf16_t sT[CIN][DT][4][48];

    for (int i = tid; i < CIN * 27; i += 256) sDW[i] = dw_w[i];
    for (int i = tid; i < CIN; i += 256) sDB[i] = dw_b[i];
    __syncthreads();

    // ---------------- phase 1: depthwise ----------------
    for (int idx = tid; idx < CIN * 12; idx += 256) {
        const int ci = idx / 12;
        const int wq = idx - ci * 12;
        const int w0g = wbase + wq * 4;

        float K[27];
#pragma unroll
        for (int k = 0; k < 27; ++k) K[k] = sDW[ci * 27 + k];

        float acc[DT][4][4];
#pragma unroll
        for (int dl = 0; dl < DT; ++dl)
#pragma unroll
            for (int a = 0; a < 4; ++a)
#pragma unroll
                for (int c = 0; c < 4; ++c) acc[dl][a][c] = 0.f;

        const TIN* plane0 = x + (size_t)(b * CIN + ci) * DIN * HIN * WIN;
        constexpr int NP = S * (DT - 1) + 3;
#pragma unroll
        for (int p = 0; p < NP; ++p) {
            const int din = S * d0 - 1 + p;
            if (din < 0 || din >= DIN) continue;       // block-uniform
            const TIN* pl = plane0 + (size_t)din * HIN * WIN;
#pragma unroll
            for (int r = 0; r < 3 * S + 3; ++r) {
                const int hin = h0 * S - 1 + r;
                if (hin < 0 || hin >= HIN) continue;   // block-uniform
                const TIN* rowp = pl + (size_t)hin * WIN + w0g * S;
                // win[j] = x[w0g*S - 1 + j], j = 0 .. 3S+2
                float win[3 * S + 3];
                win[0] = (w0g > 0) ? ld1(rowp - 1) : 0.f;
                {
                    const float4 Bv = ld4(rowp);
                    win[1] = Bv.x; win[2] = Bv.y; win[3] = Bv.z; win[4] = Bv.w;
                }
                if constexpr (S == 1) {
                    win[5] = (w0g + 4 < WIN) ? ld1(rowp + 4) : 0.f;
                } else {
                    const float4 Cv = ld4(rowp + 4);   // in-bounds for S=2
                    win[5] = Cv.x; win[6] = Cv.y; win[7] = Cv.z; win[8] = Cv.w;
                }
#pragma unroll
                for (int dl = 0; dl < DT; ++dl) {
                    const int kd = p - S * dl;         // compile-time
                    if (kd < 0 || kd > 2) continue;
#pragma unroll
                    for (int hh = 0; hh < 4; ++hh) {
                        const int kh = r - S * hh;     // compile-time
                        if (kh < 0 || kh > 2) continue;
#pragma unroll
                        for (int ww = 0; ww < 4; ++ww) {
#pragma unroll
                            for (int kw = 0; kw < 3; ++kw)
                                acc[dl][hh][ww] = fmaf(win[ww * S + kw],
                                                       K[kd * 9 + kh * 3 + kw],
                                                       acc[dl][hh][ww]);
                        }
                    }
                }
            }
        }
        const float bia = sDB[ci];
#pragma unroll
        for (int dl = 0; dl < DT; ++dl) {
#pragma unroll
            for (int hh = 0; hh < 4; ++hh) {
                float t0 = acc[dl][hh][0] + bia, t1 = acc[dl][hh][1] + bia;
                float t2 = acc[dl][hh][2] + bia, t3 = acc[dl][hh][3] + bia;
                ushort4 o;
                o.x = f2b(fmaxf(t0, 0.1f * t0));
                o.y = f2b(fmaxf(t1, 0.1f * t1));
                o.z = f2b(fmaxf(t2, 0.1f * t2));
                o.w = f2b(fmaxf(t3, 0.1f * t3));
                *(ushort4*)&sT[ci][dl][hh][wq * 4] = o;
            }
        }
    }
    __syncthreads();

    // ---------------- phase 2: pointwise ----------------
    for (int t = tid; t < DT * 192; t += 256) {
        const int dl  = t / 192;
        const int rem = t - dl * 192;
        const int hh  = rem / 48;
        const int ww  = rem - hh * 48;
        if (d0 + dl >= DO) continue;                   // tail guard (block4)
        float L[CIN];
#pragma unroll
        for (int ci = 0; ci < CIN; ++ci) L[ci] = b2f(sT[ci][dl][hh][ww]);
        const size_t planeSz = (size_t)DO * HO * WO;
        TOUT* yb = y + (size_t)b * COUT * planeSz + (size_t)(d0 + dl) * HO * WO
                     + (size_t)(h0 + hh) * WO + (wbase + ww);
        for (int co = 0; co < COUT; ++co) {
            float s = pw_b[co];                        // uniform -> s_load
#pragma unroll
            for (int ci = 0; ci < CIN; ++ci)
                s = fmaf(pw_w[co * CIN + ci], L[ci], s);
            st1(yb + (size_t)co * planeSz, fmaxf(s, 0.1f * s));
        }
    }
}

// ---------------------------------------------------------------------------
extern "C" void kernel_launch(void* const* d_in, const int* in_sizes, int n_in,
                              void* d_out, int out_size, void* d_ws, size_t ws_size,
                              hipStream_t stream) {
    const float* rgb  = (const float*)d_in[0];
    const float* dep  = (const float*)d_in[1];
    const float* dw1w = (const float*)d_in[2];
    const float* dw1b = (const float*)d_in[3];
    const float* pw1w = (const float*)d_in[4];
    const float* pw1b = (const float*)d_in[5];
    const float* dw2w = (const float*)d_in[6];
    const float* dw2b = (const float*)d_in[7];
    const float* pw2w = (const float*)d_in[8];
    const float* pw2b = (const float*)d_in[9];
    const float* dw3w = (const float*)d_in[10];
    const float* dw3b = (const float*)d_in[11];
    const float* pw3w = (const float*)d_in[12];
    const float* pw3b = (const float*)d_in[13];
    const float* dw4w = (const float*)d_in[14];
    const float* dw4b = (const float*)d_in[15];
    const float* pw4w = (const float*)d_in[16];
    const float* pw4b = (const float*)d_in[17];

    const size_t HALF = 78643200;
    bf16_t* corrO = (bf16_t*)d_ws;
    bf16_t* rgbT  = (bf16_t*)((char*)d_ws + HALF);
    bf16_t* depT  = (bf16_t*)((char*)d_ws + HALF + 12582912);
    bf16_t* b1o   = (bf16_t*)((char*)d_ws + HALF);   // rgbT/depT dead by then
    float*  b2o   = (float*)d_ws;                    // corrO dead by then
    float*  b3o   = (float*)((char*)d_ws + HALF);    // b1o dead by then
    float*  outp  = (float*)d_out;

    transpose_bf16<<<dim3(512, 2), 256, 0, stream>>>(rgb, dep, rgbT, depT);

    corr_mfma<<<dim3(20, 64, 8), 256, 0, stream>>>(rgbT, depT, corrO);

    fused_block<20, 20, 1, 2, 20, 64, 192, 20, 64, 192, bf16_t, bf16_t>
        <<<dim3(64, 10, 8), 256, 0, stream>>>(corrO, dw1w, dw1b, pw1w, pw1b, b1o);

    fused_block<20, 40, 2, 2, 20, 64, 192, 10, 32, 96, bf16_t, float>
        <<<dim3(16, 5, 8), 256, 0, stream>>>(b1o, dw2w, dw2b, pw2w, pw2b, b2o);

    fused_block<40, 40, 1, 2, 10, 32, 96, 10, 32, 96, float, float>
        <<<dim3(16, 5, 8), 256, 0, stream>>>(b2o, dw3w, dw3b, pw3w, pw3b, b3o);

    fused_block<40, 80, 2, 2, 10, 32, 96, 5, 16, 48, float, float>
        <<<dim3(4, 3, 8), 256, 0, stream>>>(b3o, dw4w, dw4b, pw4w, pw4b, outp);
}

// Round 4
// 477.412 us; speedup vs baseline: 1.0973x; 1.0973x over previous
//
#include <hip/hip_runtime.h>
#include <cstdint>
#include <cstddef>

// ---------------------------------------------------------------------------
// feature_matching: corr(P=20, C=64) -> 4x (depthwise 3^3 + pointwise) blocks
//
// R4: pointwise phase on MFMA. Phase 1 (depthwise, DT=2 merged-plane) writes
// channels-last bf16 LDS sT[dl][hh][w][ci]; phase 2 per wave: M=16 w-pos x
// N=16 co x K=32 ci bf16 MFMA (A-frag in-register zero-pad for ci>=CIN,
// B-frag = pw weights gathered once per block). corr path unchanged.
//
// ws layout (peak 157,286,400 B):
//   [0,        78.6MB): corrO (bf16)        -> later b2o (fp32, 39.3MB)
//   [78.6MB,  157.3MB): rgbT+depT (bf16)    -> later b1o (bf16, 78.6MB)
//                                           -> later b3o (fp32, 39.3MB)
// ---------------------------------------------------------------------------

typedef unsigned short bf16_t;
typedef __attribute__((ext_vector_type(8))) short short8;
typedef __attribute__((ext_vector_type(4))) short short4_t;
typedef __attribute__((ext_vector_type(4))) float f32x4;

static __device__ inline float b2f(bf16_t u) {
    union { float f; uint32_t i; } v; v.i = ((uint32_t)u) << 16; return v.f;
}
static __device__ inline bf16_t f2b(float f) {
    union { float f; uint32_t i; } v; v.f = f;
    uint32_t r = v.i + 0x7fffu + ((v.i >> 16) & 1u);  // round-nearest-even
    return (bf16_t)(r >> 16);
}

static __device__ inline float4 ld4(const float* p) { return *(const float4*)p; }
static __device__ inline float4 ld4(const bf16_t* p) {
    ushort4 u = *(const ushort4*)p;
    return make_float4(b2f(u.x), b2f(u.y), b2f(u.z), b2f(u.w));
}
static __device__ inline float ld1(const float* p) { return *p; }
static __device__ inline float ld1(const bf16_t* p) { return b2f(*p); }
static __device__ inline void st1(float* p, float v) { *p = v; }
static __device__ inline void st1(bf16_t* p, float v) { *p = f2b(v); }

// ---------------------------------------------------------------------------
// Prepass: (b,c,h,w) fp32 -> (b,h,w,c) bf16, LDS tile transpose per (b,h).
// ---------------------------------------------------------------------------
__global__ __launch_bounds__(256) void transpose_bf16(
        const float* __restrict__ rgb, const float* __restrict__ dep,
        bf16_t* __restrict__ rgbT, bf16_t* __restrict__ depT) {
    const int bh = blockIdx.x;
    const float* src = blockIdx.y ? dep : rgb;
    bf16_t* dst = blockIdx.y ? depT : rgbT;
    const int tid = threadIdx.x;
    const int b = bh >> 6, h = bh & 63;

    __shared__ bf16_t S[64 * 194];

    const float* srcb = src + (size_t)b * 786432 + (size_t)h * 192;
#pragma unroll
    for (int it = 0; it < 12; ++it) {
        const int idx = it * 256 + tid;      // 3072 = 64c x 48 float4
        const int c = idx / 48, w4 = idx - c * 48;
        const float4 v = *(const float4*)(srcb + (size_t)c * 12288 + 4 * w4);
        bf16_t* sp = &S[c * 194 + 4 * w4];
        sp[0] = f2b(v.x); sp[1] = f2b(v.y); sp[2] = f2b(v.z); sp[3] = f2b(v.w);
    }
    __syncthreads();
    bf16_t* dstb = dst + (size_t)bh * 192 * 64;
#pragma unroll
    for (int it = 0; it < 12; ++it) {
        const int idx = it * 256 + tid;      // 3072 = 192w x 16 c4
        const int w = idx >> 4, c4 = idx & 15;
        ushort4 o;
        o.x = S[(4 * c4 + 0) * 194 + w];
        o.y = S[(4 * c4 + 1) * 194 + w];
        o.z = S[(4 * c4 + 2) * 194 + w];
        o.w = S[(4 * c4 + 3) * 194 + w];
        *(ushort4*)(dstb + (size_t)w * 64 + 4 * c4) = o;
    }
}

// ---------------------------------------------------------------------------
// MFMA correlation (unchanged from R2).
// ---------------------------------------------------------------------------
__global__ __launch_bounds__(256) void corr_mfma(
        const bf16_t* __restrict__ rgbT, const bf16_t* __restrict__ depT,
        bf16_t* __restrict__ out) {
    const int di = blockIdx.x, h = blockIdx.y, b = blockIdx.z;
    const int tid = threadIdx.x;
    const int hd = h + di - 10;
    bf16_t* outb = out + ((size_t)((b * 20 + di) * 20) * 64 + h) * 192;

    if (hd < 0 || hd >= 64) {            // depth row fully in zero-pad
#pragma unroll
        for (int it = 0; it < 4; ++it) {
            const int idx = it * 256 + tid;
            if (idx < 960) {
                const int dj = idx / 48, w4 = idx - dj * 48;
                *(ushort4*)(outb + (size_t)dj * 12288 + 4 * w4) =
                    make_ushort4(0, 0, 0, 0);
            }
        }
        return;
    }

    __shared__ float Dall[4080];         // addr = w*21 + (w>>2) + dj
    const int lane = tid & 63, wave = tid >> 6;
    const int n = lane & 15, q = lane >> 4;

    const bf16_t* Abase = rgbT + (size_t)(b * 64 + h) * 192 * 64;
    const bf16_t* Bbase = depT + (size_t)(b * 64 + hd) * 192 * 64;

#pragma unroll
    for (int t = 0; t < 3; ++t) {
        const int w0 = wave * 48 + t * 16;
        const short8* Ap = (const short8*)(Abase + (size_t)(w0 + n) * 64 + q * 8);
        const short8 a0 = Ap[0];         // c = q*8 .. q*8+7
        const short8 a1 = Ap[4];         // c += 32
        f32x4 acc[3];
#pragma unroll
        for (int ut = 0; ut < 3; ++ut) {
            acc[ut].x = 0.f; acc[ut].y = 0.f; acc[ut].z = 0.f; acc[ut].w = 0.f;
        }
#pragma unroll
        for (int ut = 0; ut < 3; ++ut) {
            const int u0 = w0 + (ut - 1) * 16;
            if (u0 >= 0 && u0 <= 176) {  // wave-uniform; OOB tile stays 0
                const short8* Bp = (const short8*)(Bbase + (size_t)(u0 + n) * 64 + q * 8);
                acc[ut] = __builtin_amdgcn_mfma_f32_16x16x32_bf16(a0, Bp[0], acc[ut], 0, 0, 0);
                acc[ut] = __builtin_amdgcn_mfma_f32_16x16x32_bf16(a1, Bp[4], acc[ut], 0, 0, 0);
            }
        }
#pragma unroll
        for (int ut = 0; ut < 3; ++ut) {
#pragma unroll
            for (int r = 0; r < 4; ++r) {
                const int dj = 16 * ut + n - 4 * q - r - 6;
                const int w = w0 + 4 * q + r;
                if (dj >= 0 && dj < 20)
                    Dall[w * 21 + (w >> 2) + dj] = acc[ut][r];
            }
        }
    }
    __syncthreads();
#pragma unroll
    for (int it = 0; it < 4; ++it) {
        const int idx = it * 256 + tid;
        if (idx < 960) {
            const int dj = idx / 48, w4 = idx - dj * 48;
            const int base = 85 * w4 + dj;   // (4*w4+j)*21 + w4 + dj
            ushort4 o;
            o.x = f2b(Dall[base]);
            o.y = f2b(Dall[base + 21]);
            o.z = f2b(Dall[base + 42]);
            o.w = f2b(Dall[base + 63]);
            *(ushort4*)(outb + (size_t)dj * 12288 + 4 * w4) = o;
        }
    }
}

// ---------------------------------------------------------------------------
// Fused block v4: DT d-planes per block, merged plane loop (phase 1 as R3)
// but channels-last bf16 LDS sT[dl][hh][w][ci]; phase 2 = MFMA GEMM:
// M = 16 w-positions (A-frag from LDS, guarded b64 loads zero-pad ci>=CIN),
// N = 16 co (B-frag = pw weights, gathered once, bf16),
// K = 32 ci per mfma (KH = ceil(CIN/32) mfmas).
// D-frag: row(q*4+reg) = w, col(lane&15) = co -> float4/ushort4 stores.
// ---------------------------------------------------------------------------
template<int CIN, int COUT, int S, int DT, int DIN, int HIN, int WIN,
         int DO, int HO, int WO, typename TIN, typename TOUT>
__global__ __launch_bounds__(256) void fused_block(
        const TIN* __restrict__ x,
        const float* __restrict__ dw_w, const float* __restrict__ dw_b,
        const float* __restrict__ pw_w, const float* __restrict__ pw_b,
        TOUT* __restrict__ y) {
    static_assert(WO % 48 == 0 && HO % 4 == 0, "tile divisibility");
    static_assert(CIN % 4 == 0, "A-frag guard needs CIN % 4 == 0");
    constexpr int WT = WO / 48;
    const int wt = blockIdx.x % WT;
    const int ht = blockIdx.x / WT;
    const int d0 = blockIdx.y * DT;
    const int b  = blockIdx.z;
    const int tid = threadIdx.x;
    const int h0 = ht * 4;
    const int wbase = wt * 48;

    __shared__ float  sDW[CIN * 27];
    __shared__ float  sDB[CIN];
    __shared__ bf16_t sT[DT * 4 * 48 * CIN];   // [dl][hh][w][ci]

    for (int i = tid; i < CIN * 27; i += 256) sDW[i] = dw_w[i];
    for (int i = tid; i < CIN; i += 256) sDB[i] = dw_b[i];
    __syncthreads();

    // ---------------- phase 1: depthwise ----------------
    for (int idx = tid; idx < CIN * 12; idx += 256) {
        const int ci = idx / 12;
        const int wq = idx - ci * 12;
        const int w0g = wbase + wq * 4;

        float K[27];
#pragma unroll
        for (int k = 0; k < 27; ++k) K[k] = sDW[ci * 27 + k];

        float acc[DT][4][4];
#pragma unroll
        for (int dl = 0; dl < DT; ++dl)
#pragma unroll
            for (int a = 0; a < 4; ++a)
#pragma unroll
                for (int c = 0; c < 4; ++c) acc[dl][a][c] = 0.f;

        const TIN* plane0 = x + (size_t)(b * CIN + ci) * DIN * HIN * WIN;
        constexpr int NP = S * (DT - 1) + 3;
#pragma unroll
        for (int p = 0; p < NP; ++p) {
            const int din = S * d0 - 1 + p;
            if (din < 0 || din >= DIN) continue;       // block-uniform
            const TIN* pl = plane0 + (size_t)din * HIN * WIN;
#pragma unroll
            for (int r = 0; r < 3 * S + 3; ++r) {
                const int hin = h0 * S - 1 + r;
                if (hin < 0 || hin >= HIN) continue;   // block-uniform
                const TIN* rowp = pl + (size_t)hin * WIN + w0g * S;
                // win[j] = x[w0g*S - 1 + j], j = 0 .. 3S+2
                float win[3 * S + 3];
                win[0] = (w0g > 0) ? ld1(rowp - 1) : 0.f;
                {
                    const float4 Bv = ld4(rowp);
                    win[1] = Bv.x; win[2] = Bv.y; win[3] = Bv.z; win[4] = Bv.w;
                }
                if constexpr (S == 1) {
                    win[5] = (w0g + 4 < WIN) ? ld1(rowp + 4) : 0.f;
                } else {
                    const float4 Cv = ld4(rowp + 4);   // in-bounds for S=2
                    win[5] = Cv.x; win[6] = Cv.y; win[7] = Cv.z; win[8] = Cv.w;
                }
#pragma unroll
                for (int dl = 0; dl < DT; ++dl) {
                    const int kd = p - S * dl;         // compile-time
                    if (kd < 0 || kd > 2) continue;
#pragma unroll
                    for (int hh = 0; hh < 4; ++hh) {
                        const int kh = r - S * hh;     // compile-time
                        if (kh < 0 || kh > 2) continue;
#pragma unroll
                        for (int ww = 0; ww < 4; ++ww) {
#pragma unroll
                            for (int kw = 0; kw < 3; ++kw)
                                acc[dl][hh][ww] = fmaf(win[ww * S + kw],
                                                       K[kd * 9 + kh * 3 + kw],
                                                       acc[dl][hh][ww]);
                        }
                    }
                }
            }
        }
        const float bia = sDB[ci];
#pragma unroll
        for (int dl = 0; dl < DT; ++dl) {
#pragma unroll
            for (int hh = 0; hh < 4; ++hh) {
#pragma unroll
                for (int ww = 0; ww < 4; ++ww) {
                    const float t = acc[dl][hh][ww] + bia;
                    sT[((dl * 4 + hh) * 48 + wq * 4 + ww) * CIN + ci] =
                        f2b(fmaxf(t, 0.1f * t));
                }
            }
        }
    }
    __syncthreads();

    // ---------------- phase 2: pointwise via MFMA ----------------
    constexpr int NT = (COUT + 15) / 16;   // co tiles
    constexpr int KH = (CIN + 31) / 32;    // K=32 chunks
    const int lane = tid & 63, wave = tid >> 6;
    const int m15 = lane & 15, q = lane >> 4;

    // B fragments: B[k=ci][n=co], lane&15 = co, k = q*8+j. Gathered once.
    short8 bf[NT][KH];
    float  pb[NT];
#pragma unroll
    for (int nt = 0; nt < NT; ++nt) {
        const int co = nt * 16 + m15;
        pb[nt] = (co < COUT) ? pw_b[co] : 0.f;
#pragma unroll
        for (int kh = 0; kh < KH; ++kh) {
            union { short8 v; short e[8]; } u;
#pragma unroll
            for (int j = 0; j < 8; ++j) {
                const int ci = kh * 32 + q * 8 + j;
                u.e[j] = (co < COUT && ci < CIN)
                         ? (short)f2b(pw_w[co * CIN + ci]) : (short)0;
            }
            bf[nt][kh] = u.v;
        }
    }

    const size_t planeSz = (size_t)DO * HO * WO;
    // M tiles: DT*4*3 tiles of 16 w-positions, DT*3 per wave.
    for (int mt = wave * DT * 3; mt < (wave + 1) * DT * 3; ++mt) {
        const int dl  = mt / 12;
        const int rem = mt - dl * 12;
        const int hh  = rem / 3;
        const int w0  = (rem - hh * 3) * 16;
        if (d0 + dl >= DO) continue;           // tail guard (block4)

        const bf16_t* ap = &sT[((dl * 4 + hh) * 48 + w0 + m15) * CIN];
        union { short8 v; struct { short4_t lo, hi; } h; } af[KH];
#pragma unroll
        for (int kh = 0; kh < KH; ++kh) {
            af[kh].h.lo = (short4_t)0;
            af[kh].h.hi = (short4_t)0;
            const int ci0 = kh * 32 + q * 8;
            if (ci0 < CIN)     af[kh].h.lo = *(const short4_t*)(ap + ci0);
            if (ci0 + 4 < CIN) af[kh].h.hi = *(const short4_t*)(ap + ci0 + 4);
        }
#pragma unroll
        for (int nt = 0; nt < NT; ++nt) {
            f32x4 acc;
            acc.x = 0.f; acc.y = 0.f; acc.z = 0.f; acc.w = 0.f;
#pragma unroll
            for (int kh = 0; kh < KH; ++kh)
                acc = __builtin_amdgcn_mfma_f32_16x16x32_bf16(
                          af[kh].v, bf[nt][kh], acc, 0, 0, 0);
            const int co = nt * 16 + m15;
            if (co < COUT) {
                const float bias = pb[nt];
                TOUT* yp = y + (size_t)b * COUT * planeSz + (size_t)co * planeSz
                             + (size_t)(d0 + dl) * HO * WO
                             + (size_t)(h0 + hh) * WO + wbase + w0 + q * 4;
                float s0 = acc.x + bias, s1 = acc.y + bias;
                float s2 = acc.z + bias, s3 = acc.w + bias;
                s0 = fmaxf(s0, 0.1f * s0); s1 = fmaxf(s1, 0.1f * s1);
                s2 = fmaxf(s2, 0.1f * s2); s3 = fmaxf(s3, 0.1f * s3);
                if constexpr (sizeof(TOUT) == 4) {
                    float4 o; o.x = s0; o.y = s1; o.z = s2; o.w = s3;
                    *(float4*)yp = o;
                } else {
                    ushort4 o;
                    o.x = f2b(s0); o.y = f2b(s1); o.z = f2b(s2); o.w = f2b(s3);
                    *(ushort4*)yp = o;
                }
            }
        }
    }
}

// ---------------------------------------------------------------------------
extern "C" void kernel_launch(void* const* d_in, const int* in_sizes, int n_in,
                              void* d_out, int out_size, void* d_ws, size_t ws_size,
                              hipStream_t stream) {
    const float* rgb  = (const float*)d_in[0];
    const float* dep  = (const float*)d_in[1];
    const float* dw1w = (const float*)d_in[2];
    const float* dw1b = (const float*)d_in[3];
    const float* pw1w = (const float*)d_in[4];
    const float* pw1b = (const float*)d_in[5];
    const float* dw2w = (const float*)d_in[6];
    const float* dw2b = (const float*)d_in[7];
    const float* pw2w = (const float*)d_in[8];
    const float* pw2b = (const float*)d_in[9];
    const float* dw3w = (const float*)d_in[10];
    const float* dw3b = (const float*)d_in[11];
    const float* pw3w = (const float*)d_in[12];
    const float* pw3b = (const float*)d_in[13];
    const float* dw4w = (const float*)d_in[14];
    const float* dw4b = (const float*)d_in[15];
    const float* pw4w = (const float*)d_in[16];
    const float* pw4b = (const float*)d_in[17];

    const size_t HALF = 78643200;
    bf16_t* corrO = (bf16_t*)d_ws;
    bf16_t* rgbT  = (bf16_t*)((char*)d_ws + HALF);
    bf16_t* depT  = (bf16_t*)((char*)d_ws + HALF + 12582912);
    bf16_t* b1o   = (bf16_t*)((char*)d_ws + HALF);   // rgbT/depT dead by then
    float*  b2o   = (float*)d_ws;                    // corrO dead by then
    float*  b3o   = (float*)((char*)d_ws + HALF);    // b1o dead by then
    float*  outp  = (float*)d_out;

    transpose_bf16<<<dim3(512, 2), 256, 0, stream>>>(rgb, dep, rgbT, depT);

    corr_mfma<<<dim3(20, 64, 8), 256, 0, stream>>>(rgbT, depT, corrO);

    fused_block<20, 20, 1, 2, 20, 64, 192, 20, 64, 192, bf16_t, bf16_t>
        <<<dim3(64, 10, 8), 256, 0, stream>>>(corrO, dw1w, dw1b, pw1w, pw1b, b1o);

    fused_block<20, 40, 2, 2, 20, 64, 192, 10, 32, 96, bf16_t, float>
        <<<dim3(16, 5, 8), 256, 0, stream>>>(b1o, dw2w, dw2b, pw2w, pw2b, b2o);

    fused_block<40, 40, 1, 2, 10, 32, 96, 10, 32, 96, float, float>
        <<<dim3(16, 5, 8), 256, 0, stream>>>(b2o, dw3w, dw3b, pw3w, pw3b, b3o);

    fused_block<40, 80, 2, 2, 10, 32, 96, 5, 16, 48, float, float>
        <<<dim3(4, 3, 8), 256, 0, stream>>>(b3o, dw4w, dw4b, pw4w, pw4b, outp);
}

// Round 5
// 434.221 us; speedup vs baseline: 1.2064x; 1.0995x over previous
//
#include <hip/hip_runtime.h>
#include <cstdint>
#include <cstddef>

// ---------------------------------------------------------------------------
// feature_matching: corr(P=20, C=64) -> 4x (depthwise 3^3 + pointwise) blocks
//
// R5: all intermediates f16 (better precision than bf16, same bytes) and
// depthwise via v_dot2_f32_f16 (2 MAC/inst, fp32 accum, zero unpack cost:
// packed pairs come from dword loads + v_alignbit). sT stride padded
// (CINP=CIN+4) to kill ds_write bank conflicts. b4 DT=1 (tail fill).
// corr path: f16 MFMA. pointwise: f16 MFMA.
//
// ws layout (peak 157,286,400 B):
//   [0,        78.6MB): corrO (f16)        -> later b2o (f16, 19.7MB)
//   [78.6MB,  157.3MB): rgbT+depT (f16)    -> later b1o (f16, 78.6MB)
//                                          -> later b3o (f16, 19.7MB)
// ---------------------------------------------------------------------------

typedef unsigned short u16;
typedef _Float16 f16_t;
typedef __attribute__((ext_vector_type(2))) _Float16 half2_t;
typedef __attribute__((ext_vector_type(4))) _Float16 half4_t;
typedef __attribute__((ext_vector_type(8))) _Float16 half8_t;
typedef __attribute__((ext_vector_type(4))) float f32x4;

static __device__ inline u16 f2h(float f) {
    union { f16_t h; u16 u; } v; v.h = (f16_t)f; return v.u;
}
static __device__ inline float h2f(u16 u) {
    union { f16_t h; u16 u; } v; v.u = u; return (float)v.h;
}
static __device__ inline half2_t H2(uint32_t u) {
    union { uint32_t u; half2_t h; } v; v.u = u; return v.h;
}

#if __has_builtin(__builtin_amdgcn_fdot2)
static __device__ inline float FDOT2(half2_t a, half2_t b, float c) {
    return __builtin_amdgcn_fdot2(a, b, c, false);
}
#else
static __device__ inline float FDOT2(half2_t a, half2_t b, float c) {
    return fmaf((float)a.x, (float)b.x, fmaf((float)a.y, (float)b.y, c));
}
#endif

#if __has_builtin(__builtin_amdgcn_alignbit)
static __device__ inline uint32_t mkp(uint32_t lo, uint32_t hi) {
    return __builtin_amdgcn_alignbit(hi, lo, 16);   // (lo.hi16, hi.lo16)
}
#else
static __device__ inline uint32_t mkp(uint32_t lo, uint32_t hi) {
    return (lo >> 16) | (hi << 16);
}
#endif

static __device__ inline uint32_t ldu(const u16* p) { return *(const uint32_t*)p; }

// ---------------------------------------------------------------------------
// Prepass: (b,c,h,w) fp32 -> (b,h,w,c) f16, LDS tile transpose per (b,h).
// ---------------------------------------------------------------------------
__global__ __launch_bounds__(256) void transpose_f16(
        const float* __restrict__ rgb, const float* __restrict__ dep,
        u16* __restrict__ rgbT, u16* __restrict__ depT) {
    const int bh = blockIdx.x;
    const float* src = blockIdx.y ? dep : rgb;
    u16* dst = blockIdx.y ? depT : rgbT;
    const int tid = threadIdx.x;
    const int b = bh >> 6, h = bh & 63;

    __shared__ u16 S[64 * 194];

    const float* srcb = src + (size_t)b * 786432 + (size_t)h * 192;
#pragma unroll
    for (int it = 0; it < 12; ++it) {
        const int idx = it * 256 + tid;      // 3072 = 64c x 48 float4
        const int c = idx / 48, w4 = idx - c * 48;
        const float4 v = *(const float4*)(srcb + (size_t)c * 12288 + 4 * w4);
        u16* sp = &S[c * 194 + 4 * w4];
        sp[0] = f2h(v.x); sp[1] = f2h(v.y); sp[2] = f2h(v.z); sp[3] = f2h(v.w);
    }
    __syncthreads();
    u16* dstb = dst + (size_t)bh * 192 * 64;
#pragma unroll
    for (int it = 0; it < 12; ++it) {
        const int idx = it * 256 + tid;      // 3072 = 192w x 16 c4
        const int w = idx >> 4, c4 = idx & 15;
        ushort4 o;
        o.x = S[(4 * c4 + 0) * 194 + w];
        o.y = S[(4 * c4 + 1) * 194 + w];
        o.z = S[(4 * c4 + 2) * 194 + w];
        o.w = S[(4 * c4 + 3) * 194 + w];
        *(ushort4*)(dstb + (size_t)w * 64 + 4 * c4) = o;
    }
}

// ---------------------------------------------------------------------------
// MFMA correlation (R2 structure, f16 MFMA).
// ---------------------------------------------------------------------------
__global__ __launch_bounds__(256) void corr_mfma(
        const u16* __restrict__ rgbT, const u16* __restrict__ depT,
        u16* __restrict__ out) {
    const int di = blockIdx.x, h = blockIdx.y, b = blockIdx.z;
    const int tid = threadIdx.x;
    const int hd = h + di - 10;
    u16* outb = out + ((size_t)((b * 20 + di) * 20) * 64 + h) * 192;

    if (hd < 0 || hd >= 64) {            // depth row fully in zero-pad
#pragma unroll
        for (int it = 0; it < 4; ++it) {
            const int idx = it * 256 + tid;
            if (idx < 960) {
                const int dj = idx / 48, w4 = idx - dj * 48;
                *(ushort4*)(outb + (size_t)dj * 12288 + 4 * w4) =
                    make_ushort4(0, 0, 0, 0);
            }
        }
        return;
    }

    __shared__ float Dall[4080];         // addr = w*21 + (w>>2) + dj
    const int lane = tid & 63, wave = tid >> 6;
    const int n = lane & 15, q = lane >> 4;

    const u16* Abase = rgbT + (size_t)(b * 64 + h) * 192 * 64;
    const u16* Bbase = depT + (size_t)(b * 64 + hd) * 192 * 64;

#pragma unroll
    for (int t = 0; t < 3; ++t) {
        const int w0 = wave * 48 + t * 16;
        const half8_t* Ap = (const half8_t*)(Abase + (size_t)(w0 + n) * 64 + q * 8);
        const half8_t a0 = Ap[0];        // c = q*8 .. q*8+7
        const half8_t a1 = Ap[4];        // c += 32
        f32x4 acc[3];
#pragma unroll
        for (int ut = 0; ut < 3; ++ut) {
            acc[ut].x = 0.f; acc[ut].y = 0.f; acc[ut].z = 0.f; acc[ut].w = 0.f;
        }
#pragma unroll
        for (int ut = 0; ut < 3; ++ut) {
            const int u0 = w0 + (ut - 1) * 16;
            if (u0 >= 0 && u0 <= 176) {  // wave-uniform; OOB tile stays 0
                const half8_t* Bp = (const half8_t*)(Bbase + (size_t)(u0 + n) * 64 + q * 8);
                acc[ut] = __builtin_amdgcn_mfma_f32_16x16x32_f16(a0, Bp[0], acc[ut], 0, 0, 0);
                acc[ut] = __builtin_amdgcn_mfma_f32_16x16x32_f16(a1, Bp[4], acc[ut], 0, 0, 0);
            }
        }
#pragma unroll
        for (int ut = 0; ut < 3; ++ut) {
#pragma unroll
            for (int r = 0; r < 4; ++r) {
                const int dj = 16 * ut + n - 4 * q - r - 6;
                const int w = w0 + 4 * q + r;
                if (dj >= 0 && dj < 20)
                    Dall[w * 21 + (w >> 2) + dj] = acc[ut][r];
            }
        }
    }
    __syncthreads();
#pragma unroll
    for (int it = 0; it < 4; ++it) {
        const int idx = it * 256 + tid;
        if (idx < 960) {
            const int dj = idx / 48, w4 = idx - dj * 48;
            const int base = 85 * w4 + dj;   // (4*w4+j)*21 + w4 + dj
            ushort4 o;
            o.x = f2h(Dall[base]);
            o.y = f2h(Dall[base + 21]);
            o.z = f2h(Dall[base + 42]);
            o.w = f2h(Dall[base + 63]);
            *(ushort4*)(outb + (size_t)dj * 12288 + 4 * w4) = o;
        }
    }
}

// ---------------------------------------------------------------------------
// Fused block v5: f16 in, fdot2 depthwise (fp32 accum), f16 MFMA pointwise.
// Phase 1: task = (ci, w-quad); per row build packed pairs from dword loads
//   (+alignbit), 2 fdot2 per (tap-row, output). sT[pos][ci] stride CINP
//   (padded) -> conflict-free ds.
// Phase 2: M=16 w-pos x N=16 co x K=32 ci f16 MFMA; A-frag guarded b64
//   loads (in-register zero-pad ci>=CIN); B = pw weights f16 (gathered once).
// ---------------------------------------------------------------------------
template<int CIN, int COUT, int S, int DT, int DIN, int HIN, int WIN,
         int DO, int HO, int WO, typename TOUT>
__global__ __launch_bounds__(256) void fused_block(
        const u16* __restrict__ x,
        const float* __restrict__ dw_w, const float* __restrict__ dw_b,
        const float* __restrict__ pw_w, const float* __restrict__ pw_b,
        TOUT* __restrict__ y) {
    static_assert(WO % 48 == 0 && HO % 4 == 0, "tile divisibility");
    constexpr int CINP = CIN + 4;          // padded LDS stride (24 / 44)
    constexpr int WT = WO / 48;
    const int wt = blockIdx.x % WT;
    const int ht = blockIdx.x / WT;
    const int d0 = blockIdx.y * DT;
    const int b  = blockIdx.z;
    const int tid = threadIdx.x;
    const int h0 = ht * 4;
    const int wbase = wt * 48;

    __shared__ float sDW[CIN * 27];
    __shared__ float sDB[CIN];
    __shared__ u16   sT[DT * 4 * 48 * CINP];   // [dl][hh][w][ci]

    for (int i = tid; i < CIN * 27; i += 256) sDW[i] = dw_w[i];
    for (int i = tid; i < CIN; i += 256) sDB[i] = dw_b[i];
    __syncthreads();

    // ---------------- phase 1: depthwise via fdot2 ----------------
    for (int idx = tid; idx < CIN * 12; idx += 256) {
        const int ci = idx / 12;
        const int wq = idx - ci * 12;
        const int w0g = wbase + wq * 4;

        half2_t KA[9], KB[9];              // (k0,k1) and (k2,0)/(0,k2)
#pragma unroll
        for (int t = 0; t < 9; ++t) {
            const int kd = t / 3, kh = t - 3 * (t / 3);
            const float k0 = sDW[ci * 27 + kd * 9 + kh * 3 + 0];
            const float k1 = sDW[ci * 27 + kd * 9 + kh * 3 + 1];
            const float k2 = sDW[ci * 27 + kd * 9 + kh * 3 + 2];
            half2_t a; a.x = (f16_t)k0; a.y = (f16_t)k1; KA[t] = a;
            half2_t bb;
            if constexpr (S == 1) { bb.x = (f16_t)k2; bb.y = (f16_t)0.f; }
            else                  { bb.x = (f16_t)0.f; bb.y = (f16_t)k2; }
            KB[t] = bb;
        }

        float acc[DT][4][4];
#pragma unroll
        for (int dl = 0; dl < DT; ++dl)
#pragma unroll
            for (int a = 0; a < 4; ++a)
#pragma unroll
                for (int c = 0; c < 4; ++c) acc[dl][a][c] = 0.f;

        const u16* plane0 = x + (size_t)(b * CIN + ci) * DIN * HIN * WIN;
        constexpr int NP = S * (DT - 1) + 3;
#pragma unroll
        for (int p = 0; p < NP; ++p) {
            const int din = S * d0 - 1 + p;
            if (din < 0 || din >= DIN) continue;       // block-uniform
            const u16* pl = plane0 + (size_t)din * HIN * WIN;
#pragma unroll
            for (int r = 0; r < 3 * S + 3; ++r) {
                const int hin = h0 * S - 1 + r;
                if (hin < 0 || hin >= HIN) continue;   // block-uniform
                const u16* rowp = pl + (size_t)hin * WIN + w0g * S;
                uint32_t PA[4], PB[4];
                if constexpr (S == 1) {
                    // elements x[w0-2..w0+5] as dwords D0..D3
                    const uint32_t D0 = (w0g > 0) ? ldu(rowp - 2) : 0u;
                    const uint32_t D1 = ldu(rowp);
                    const uint32_t D2 = ldu(rowp + 2);
                    const uint32_t D3 = (w0g + 4 < WIN) ? ldu(rowp + 4) : 0u;
                    const uint32_t m01 = mkp(D0, D1);  // (x-1,x0)
                    const uint32_t m12 = mkp(D1, D2);  // (x1,x2)
                    const uint32_t m23 = mkp(D2, D3);  // (x3,x4)
                    PA[0] = m01; PA[1] = D1; PA[2] = m12; PA[3] = D2;
                    PB[0] = m12; PB[1] = D2; PB[2] = m23; PB[3] = D3;
                } else {
                    // elements x[2w0-2..2w0+7] as dwords E0..E4
                    const uint32_t E0 = (w0g > 0) ? ldu(rowp - 2) : 0u;
                    const uint32_t E1 = ldu(rowp);
                    const uint32_t E2 = ldu(rowp + 2);
                    const uint32_t E3 = ldu(rowp + 4);
                    const uint32_t E4 = ldu(rowp + 6);
                    PA[0] = mkp(E0, E1); PA[1] = mkp(E1, E2);
                    PA[2] = mkp(E2, E3); PA[3] = mkp(E3, E4);
                    PB[0] = E1; PB[1] = E2; PB[2] = E3; PB[3] = E4;
                }
#pragma unroll
                for (int dl = 0; dl < DT; ++dl) {
                    const int kd = p - S * dl;         // compile-time
                    if (kd < 0 || kd > 2) continue;
#pragma unroll
                    for (int hh = 0; hh < 4; ++hh) {
                        const int kh = r - S * hh;     // compile-time
                        if (kh < 0 || kh > 2) continue;
                        const int t = kd * 3 + kh;
#pragma unroll
                        for (int ww = 0; ww < 4; ++ww)
                            acc[dl][hh][ww] = FDOT2(H2(PB[ww]), KB[t],
                                              FDOT2(H2(PA[ww]), KA[t],
                                                    acc[dl][hh][ww]));
                    }
                }
            }
        }
        const float bia = sDB[ci];
#pragma unroll
        for (int dl = 0; dl < DT; ++dl) {
#pragma unroll
            for (int hh = 0; hh < 4; ++hh) {
#pragma unroll
                for (int ww = 0; ww < 4; ++ww) {
                    const float t = acc[dl][hh][ww] + bia;
                    sT[((dl * 4 + hh) * 48 + wq * 4 + ww) * CINP + ci] =
                        f2h(fmaxf(t, 0.1f * t));
                }
            }
        }
    }
    __syncthreads();

    // ---------------- phase 2: pointwise via f16 MFMA ----------------
    constexpr int NT = (COUT + 15) / 16;   // co tiles
    constexpr int KH = (CIN + 31) / 32;    // K=32 chunks
    const int lane = tid & 63, wave = tid >> 6;
    const int m15 = lane & 15, q = lane >> 4;

    half8_t bf[NT][KH];
    float   pb[NT];
#pragma unroll
    for (int nt = 0; nt < NT; ++nt) {
        const int co = nt * 16 + m15;
        pb[nt] = (co < COUT) ? pw_b[co] : 0.f;
#pragma unroll
        for (int kh = 0; kh < KH; ++kh) {
            union { half8_t v; f16_t e[8]; } u;
#pragma unroll
            for (int j = 0; j < 8; ++j) {
                const int ci = kh * 32 + q * 8 + j;
                u.e[j] = (co < COUT && ci < CIN)
                         ? (f16_t)pw_w[co * CIN + ci] : (f16_t)0.f;
            }
            bf[nt][kh] = u.v;
        }
    }

    const size_t planeSz = (size_t)DO * HO * WO;
    for (int mt = wave * DT * 3; mt < (wave + 1) * DT * 3; ++mt) {
        const int dl  = mt / 12;
        const int rem = mt - dl * 12;
        const int hh  = rem / 3;
        const int w0  = (rem - hh * 3) * 16;
        if (d0 + dl >= DO) continue;           // tail guard

        const u16* ap = &sT[((dl * 4 + hh) * 48 + w0 + m15) * CINP];
        union { half8_t v; half4_t h[2]; } af[KH];
#pragma unroll
        for (int kh = 0; kh < KH; ++kh) {
            af[kh].h[0] = (half4_t)(f16_t)0.f;
            af[kh].h[1] = (half4_t)(f16_t)0.f;
            const int ci0 = kh * 32 + q * 8;
            if (ci0 < CIN)     af[kh].h[0] = *(const half4_t*)(ap + ci0);
            if (ci0 + 4 < CIN) af[kh].h[1] = *(const half4_t*)(ap + ci0 + 4);
        }
#pragma unroll
        for (int nt = 0; nt < NT; ++nt) {
            f32x4 acc;
            acc.x = 0.f; acc.y = 0.f; acc.z = 0.f; acc.w = 0.f;
#pragma unroll
            for (int kh = 0; kh < KH; ++kh)
                acc = __builtin_amdgcn_mfma_f32_16x16x32_f16(
                          af[kh].v, bf[nt][kh], acc, 0, 0, 0);
            const int co = nt * 16 + m15;
            if (co < COUT) {
                const float bias = pb[nt];
                TOUT* yp = y + (size_t)b * COUT * planeSz + (size_t)co * planeSz
                             + (size_t)(d0 + dl) * HO * WO
                             + (size_t)(h0 + hh) * WO + wbase + w0 + q * 4;
                float s0 = acc.x + bias, s1 = acc.y + bias;
                float s2 = acc.z + bias, s3 = acc.w + bias;
                s0 = fmaxf(s0, 0.1f * s0); s1 = fmaxf(s1, 0.1f * s1);
                s2 = fmaxf(s2, 0.1f * s2); s3 = fmaxf(s3, 0.1f * s3);
                if constexpr (sizeof(TOUT) == 4) {
                    float4 o; o.x = s0; o.y = s1; o.z = s2; o.w = s3;
                    *(float4*)yp = o;
                } else {
                    ushort4 o;
                    o.x = f2h(s0); o.y = f2h(s1); o.z = f2h(s2); o.w = f2h(s3);
                    *(ushort4*)yp = o;
                }
            }
        }
    }
}

// ---------------------------------------------------------------------------
extern "C" void kernel_launch(void* const* d_in, const int* in_sizes, int n_in,
                              void* d_out, int out_size, void* d_ws, size_t ws_size,
                              hipStream_t stream) {
    const float* rgb  = (const float*)d_in[0];
    const float* dep  = (const float*)d_in[1];
    const float* dw1w = (const float*)d_in[2];
    const float* dw1b = (const float*)d_in[3];
    const float* pw1w = (const float*)d_in[4];
    const float* pw1b = (const float*)d_in[5];
    const float* dw2w = (const float*)d_in[6];
    const float* dw2b = (const float*)d_in[7];
    const float* pw2w = (const float*)d_in[8];
    const float* pw2b = (const float*)d_in[9];
    const float* dw3w = (const float*)d_in[10];
    const float* dw3b = (const float*)d_in[11];
    const float* pw3w = (const float*)d_in[12];
    const float* pw3b = (const float*)d_in[13];
    const float* dw4w = (const float*)d_in[14];
    const float* dw4b = (const float*)d_in[15];
    const float* pw4w = (const float*)d_in[16];
    const float* pw4b = (const float*)d_in[17];

    const size_t HALF = 78643200;
    u16* corrO = (u16*)d_ws;
    u16* rgbT  = (u16*)((char*)d_ws + HALF);
    u16* depT  = (u16*)((char*)d_ws + HALF + 12582912);
    u16* b1o   = (u16*)((char*)d_ws + HALF);   // rgbT/depT dead by then
    u16* b2o   = (u16*)d_ws;                   // corrO dead by then
    u16* b3o   = (u16*)((char*)d_ws + HALF);   // b1o dead by then
    float* outp = (float*)d_out;

    transpose_f16<<<dim3(512, 2), 256, 0, stream>>>(rgb, dep, rgbT, depT);

    corr_mfma<<<dim3(20, 64, 8), 256, 0, stream>>>(rgbT, depT, corrO);

    fused_block<20, 20, 1, 2, 20, 64, 192, 20, 64, 192, u16>
        <<<dim3(64, 10, 8), 256, 0, stream>>>(corrO, dw1w, dw1b, pw1w, pw1b, b1o);

    fused_block<20, 40, 2, 2, 20, 64, 192, 10, 32, 96, u16>
        <<<dim3(16, 5, 8), 256, 0, stream>>>(b1o, dw2w, dw2b, pw2w, pw2b, b2o);

    fused_block<40, 40, 1, 2, 10, 32, 96, 10, 32, 96, u16>
        <<<dim3(16, 5, 8), 256, 0, stream>>>(b2o, dw3w, dw3b, pw3w, pw3b, b3o);

    fused_block<40, 80, 2, 1, 10, 32, 96, 5, 16, 48, float>
        <<<dim3(4, 5, 8), 256, 0, stream>>>(b3o, dw4w, dw4b, pw4w, pw4b, outp);
}